// Round 1
// baseline (87.570 us; speedup 1.0000x reference)
//
#include <hip/hip_runtime.h>
#include <math.h>

#define NFFT    1024
#define HOP     256
#define NFRAMES 622
#define NBATCH  32
#define XLEN    160000
#define TILE_T  32      // frames per block
#define NPAIR   16      // packed complex FFTs per block (2 frames each)
#define ROW     1041    // padded LDS row stride (float2 units)
#define KBINS   513

// LDS index with intra-row pad every 64 complex to break late-stage bank conflicts
#define ZIDX(j, i) ((j)*ROW + (i) + ((i) >> 6))

__device__ __forceinline__ float2 cmulf(float2 a, float2 b) {
    return make_float2(a.x*b.x - a.y*b.y, a.x*b.y + a.y*b.x);
}

// reverse the five base-4 digits of a 10-bit index
__device__ __forceinline__ int rev4(int k) {
    return ((k & 3) << 8) | ((k & 12) << 4) | (k & 48) | ((k >> 4) & 12) | ((k >> 8) & 3);
}

__global__ __launch_bounds__(1024)
void spec_kernel(const float* __restrict__ x, const float* __restrict__ win,
                 float* __restrict__ out)
{
    __shared__ float2 zb[NPAIR * ROW];   // 133,248 B
    __shared__ float2 tw[768];           //   6,144 B  (W_1024^e, e in [0,768))

    const int tid = threadIdx.x;
    const int b   = blockIdx.y;
    const int t0  = blockIdx.x * TILE_T;

    // ---- twiddle table (once per block, f64 for accuracy) ----
    if (tid < 768) {
        double ang = -6.283185307179586476925286766559 * ((double)tid / 1024.0);
        tw[tid] = make_float2((float)cos(ang), (float)sin(ang));
    }

    // ---- load + window: pack frame pair (2j, 2j+1) into complex array j ----
    {
        const int n = tid;                    // 1024 threads == 1024 samples
        const float wn = win[n];              // real_w row 0 == fp32 hanning
        const float* xb = x + (size_t)b * XLEN;
        #pragma unroll
        for (int j = 0; j < NPAIR; ++j) {
            const int f0 = t0 + 2*j, f1 = f0 + 1;     // uniform per block
            float x0 = (f0 < NFRAMES) ? xb[f0*HOP + n] : 0.0f;
            float x1 = (f1 < NFRAMES) ? xb[f1*HOP + n] : 0.0f;
            zb[ZIDX(j, n)] = make_float2(wn*x0, wn*x1);
        }
    }
    __syncthreads();

    // ---- in-place radix-4 DIF FFT, 5 stages; output in digit-reversed order ----
    const int ja = tid >> 6;   // which of the 16 arrays
    const int s  = tid & 63;   // worker within array
    #pragma unroll
    for (int stage = 0; stage < 5; ++stage) {
        const int M = 256 >> (2*stage);   // quarter size: 256,64,16,4,1
        const int S = 1 << (2*stage);     // twiddle step: 1024/L
        #pragma unroll
        for (int u = 0; u < 4; ++u) {
            const int bf   = s + (u << 6);        // butterfly id 0..255
            const int seg  = bf / M;              // const M -> shifts
            const int m    = bf & (M - 1);
            const int base = seg*(M << 2) + m;    // seg*L + m
            float2 a  = zb[ZIDX(ja, base)];
            float2 bb = zb[ZIDX(ja, base + M)];
            float2 c  = zb[ZIDX(ja, base + 2*M)];
            float2 d  = zb[ZIDX(ja, base + 3*M)];
            float2 apc = make_float2(a.x + c.x,  a.y + c.y);
            float2 amc = make_float2(a.x - c.x,  a.y - c.y);
            float2 bpd = make_float2(bb.x + d.x, bb.y + d.y);
            float2 bmd = make_float2(bb.x - d.x, bb.y - d.y);
            float2 y0 = make_float2(apc.x + bpd.x, apc.y + bpd.y);
            float2 y2 = make_float2(apc.x - bpd.x, apc.y - bpd.y);
            float2 y1 = make_float2(amc.x + bmd.y, amc.y - bmd.x);  // amc - i*bmd
            float2 y3 = make_float2(amc.x - bmd.y, amc.y + bmd.x);  // amc + i*bmd
            float2 w1 = tw[m * S];
            float2 w2 = cmulf(w1, w1);
            float2 w3 = cmulf(w2, w1);
            zb[ZIDX(ja, base)]       = y0;
            zb[ZIDX(ja, base + M)]   = cmulf(w1, y1);
            zb[ZIDX(ja, base + 2*M)] = cmulf(w2, y2);
            zb[ZIDX(ja, base + 3*M)] = cmulf(w3, y3);
        }
        __syncthreads();
    }

    // ---- unpack real FFTs + mag/phase, coalesced over t ----
    const int kk = tid >> 5;          // 0..31  (k-group)
    const int tt = tid & 31;          // frame within tile -> lane-contiguous t
    const int t  = t0 + tt;
    const bool tvalid = (t < NFRAMES);
    const int jj  = tt >> 1;
    const bool odd = (tt & 1) != 0;

    float* magp = out;                                        // [32][513][622]
    float* php  = out + (size_t)NBATCH * KBINS * NFRAMES;     // [32][1024][622]
    const size_t magbase = (size_t)b * KBINS * NFRAMES + t;
    const size_t phbase  = (size_t)b * NFFT  * NFRAMES + t;

    for (int i = 0; i < 17; ++i) {
        const int k = kk + (i << 5);
        if (k > 512) break;           // only kk==0 reaches i==16 (k=512)
        const int r1 = rev4(k);
        const int r2 = rev4((NFFT - k) & (NFFT - 1));
        float2 z1 = zb[ZIDX(jj, r1)];
        float2 z2 = zb[ZIDX(jj, r2)];
        // F_even[k] = (Z[k] + conj(Z[N-k]))/2 ; F_odd[k] = -i(Z[k] - conj(Z[N-k]))/2
        float re = odd ? 0.5f*(z1.y + z2.y) : 0.5f*(z1.x + z2.x);
        float im = odd ? 0.5f*(z2.x - z1.x) : 0.5f*(z1.y - z2.y);  // exact +0.0 at k=0,512
        if (tvalid) {
            magp[magbase + (size_t)k * NFRAMES] = re*re + im*im;
            float ph = atan2f(im, re);
            php[phbase + (size_t)k * NFRAMES] = ph;
            if ((unsigned)(k - 1) < 511u) {   // mirror bins 513..1023
                // atan2(-im, re): exact-zero im must keep signed-zero semantics
                float phm = (im != 0.0f) ? -ph : atan2f(-im, re);
                php[phbase + (size_t)(NFFT - k) * NFRAMES] = phm;
            }
        }
    }
}

extern "C" void kernel_launch(void* const* d_in, const int* in_sizes, int n_in,
                              void* d_out, int out_size, void* d_ws, size_t ws_size,
                              hipStream_t stream) {
    const float* x  = (const float*)d_in[0];
    const float* rw = (const float*)d_in[1];   // row 0 = hanning window
    float* out = (float*)d_out;
    dim3 grid((NFRAMES + TILE_T - 1) / TILE_T, NBATCH);  // (20, 32)
    spec_kernel<<<grid, dim3(1024, 1, 1), 0, stream>>>(x, rw, out);
}

// Round 2
// 73.409 us; speedup vs baseline: 1.1929x; 1.1929x over previous
//
#include <hip/hip_runtime.h>
#include <math.h>

#define NFFT     1024
#define HOP      256
#define NFRAMES  622
#define NBATCH   32
#define XLEN     160000
#define TILE_T   16      // frames per block
#define NPAIR    8       // packed complex FFTs per block (2 frames each), 1 per wave
#define ROW      1153    // padded LDS row stride per array (float2): 1024 + 128 + 1 stagger
#define KBINS    513
#define NTHREADS 512

// intra-row pad every 8 complex: stride-4 patterns (stages 3/4) become <=2-way (free)
#define ZIDX(j, i) ((j)*ROW + (i) + ((i) >> 3))

__device__ __forceinline__ float2 cmulf(float2 a, float2 b) {
    return make_float2(a.x*b.x - a.y*b.y, a.x*b.y + a.y*b.x);
}

// reverse the five base-4 digits of a 10-bit index
__device__ __forceinline__ int rev4(int k) {
    return ((k & 3) << 8) | ((k & 12) << 4) | (k & 48) | ((k >> 4) & 12) | ((k >> 8) & 3);
}

// wave-internal ordering fence: HW processes a wave's DS ops in order; this
// just stops the compiler from migrating LDS reads above prior LDS writes.
__device__ __forceinline__ void wave_lds_fence() {
    asm volatile("s_waitcnt lgkmcnt(0)" ::: "memory");
    __builtin_amdgcn_sched_barrier(0);
}

__global__ __launch_bounds__(NTHREADS)
void spec_kernel(const float* __restrict__ x, const float* __restrict__ win,
                 float* __restrict__ out)
{
    __shared__ float2 zb[NPAIR * ROW];   // 73,792 B
    __shared__ float2 tw[768];           //  6,144 B   (total 79.9 KB -> 2 blocks/CU)

    const int tid = threadIdx.x;
    const int b   = blockIdx.y;
    const int t0  = blockIdx.x * TILE_T;
    const int wv  = tid >> 6;            // wave id == packed-array id
    const int l   = tid & 63;

    // ---- twiddle table (block-shared, f64 for accuracy) ----
    for (int e = tid; e < 768; e += NTHREADS) {
        double ang = -6.283185307179586476925286766559 * ((double)e / 1024.0);
        tw[e] = make_float2((float)cos(ang), (float)sin(ang));
    }

    // ---- wave-local load + window: frames (2wv, 2wv+1) -> complex array wv ----
    {
        const int f0 = t0 + 2*wv, f1 = f0 + 1;   // wave-uniform
        const float* xb = x + (size_t)b * XLEN;
        #pragma unroll
        for (int q = 0; q < 16; ++q) {
            const int n = (q << 6) + l;
            const float wn = win[n];             // real_w row 0 == fp32 hanning
            float x0 = (f0 < NFRAMES) ? xb[f0*HOP + n] : 0.0f;
            float x1 = (f1 < NFRAMES) ? xb[f1*HOP + n] : 0.0f;
            zb[ZIDX(wv, n)] = make_float2(wn*x0, wn*x1);
        }
    }
    __syncthreads();   // publishes tw[] (zb is wave-local so far)

    // ---- wave-local in-place radix-4 DIF FFT, 5 stages, digit-reversed output ----
    #pragma unroll
    for (int stage = 0; stage < 5; ++stage) {
        const int M = 256 >> (2*stage);   // 256,64,16,4,1
        const int S = 1 << (2*stage);
        #pragma unroll
        for (int u = 0; u < 4; ++u) {
            const int bf   = (u << 6) + l;        // butterfly id 0..255
            const int seg  = bf / M;              // const M -> shifts
            const int m    = bf & (M - 1);
            const int base = seg*(M << 2) + m;
            float2 a  = zb[ZIDX(wv, base)];
            float2 bb = zb[ZIDX(wv, base + M)];
            float2 c  = zb[ZIDX(wv, base + 2*M)];
            float2 d  = zb[ZIDX(wv, base + 3*M)];
            float2 apc = make_float2(a.x + c.x,  a.y + c.y);
            float2 amc = make_float2(a.x - c.x,  a.y - c.y);
            float2 bpd = make_float2(bb.x + d.x, bb.y + d.y);
            float2 bmd = make_float2(bb.x - d.x, bb.y - d.y);
            float2 y0 = make_float2(apc.x + bpd.x, apc.y + bpd.y);
            float2 y2 = make_float2(apc.x - bpd.x, apc.y - bpd.y);
            float2 y1 = make_float2(amc.x + bmd.y, amc.y - bmd.x);  // amc - i*bmd
            float2 y3 = make_float2(amc.x - bmd.y, amc.y + bmd.x);  // amc + i*bmd
            float2 w1 = tw[m * S];
            float2 w2 = cmulf(w1, w1);
            float2 w3 = cmulf(w2, w1);
            zb[ZIDX(wv, base)]       = y0;
            zb[ZIDX(wv, base + M)]   = cmulf(w1, y1);
            zb[ZIDX(wv, base + 2*M)] = cmulf(w2, y2);
            zb[ZIDX(wv, base + 3*M)] = cmulf(w3, y3);
        }
        wave_lds_fence();   // wave-synchronous: no block barrier needed
    }
    __syncthreads();   // publish all arrays for the cross-wave output phase

    // ---- unpack real FFTs + mag/phase, coalesced over t ----
    const int kk = tid >> 4;          // 0..31  (k-group)
    const int tt = tid & 15;          // frame within tile -> lane-contiguous t
    const int t  = t0 + tt;
    const bool tvalid = (t < NFRAMES);
    const int jj  = tt >> 1;
    const bool odd = (tt & 1) != 0;

    float* magp = out;                                        // [32][513][622]
    float* php  = out + (size_t)NBATCH * KBINS * NFRAMES;     // [32][1024][622]
    const size_t magbase = (size_t)b * KBINS * NFRAMES + t;
    const size_t phbase  = (size_t)b * NFFT  * NFRAMES + t;

    for (int i = 0; i < 17; ++i) {
        const int k = kk + (i << 5);
        if (k > 512) break;           // only kk==0 reaches i==16 (k=512)
        const int r1 = rev4(k);
        const int r2 = rev4((NFFT - k) & (NFFT - 1));
        float2 z1 = zb[ZIDX(jj, r1)];
        float2 z2 = zb[ZIDX(jj, r2)];
        // F_even[k] = (Z[k] + conj(Z[N-k]))/2 ; F_odd[k] = -i(Z[k] - conj(Z[N-k]))/2
        float re = odd ? 0.5f*(z1.y + z2.y) : 0.5f*(z1.x + z2.x);
        float im = odd ? 0.5f*(z2.x - z1.x) : 0.5f*(z1.y - z2.y);  // exact +0.0 at k=0,512
        if (tvalid) {
            magp[magbase + (size_t)k * NFRAMES] = re*re + im*im;
            float ph = atan2f(im, re);
            php[phbase + (size_t)k * NFRAMES] = ph;
            if ((unsigned)(k - 1) < 511u) {   // mirror bins 513..1023
                // atan2(-im, re): exact-zero im must keep signed-zero semantics
                float phm = (im != 0.0f) ? -ph : atan2f(-im, re);
                php[phbase + (size_t)(NFFT - k) * NFRAMES] = phm;
            }
        }
    }
}

extern "C" void kernel_launch(void* const* d_in, const int* in_sizes, int n_in,
                              void* d_out, int out_size, void* d_ws, size_t ws_size,
                              hipStream_t stream) {
    const float* x  = (const float*)d_in[0];
    const float* rw = (const float*)d_in[1];   // row 0 = hanning window
    float* out = (float*)d_out;
    dim3 grid((NFRAMES + TILE_T - 1) / TILE_T, NBATCH);  // (39, 32)
    spec_kernel<<<grid, dim3(NTHREADS, 1, 1), 0, stream>>>(x, rw, out);
}

// Round 3
// 52.033 us; speedup vs baseline: 1.6830x; 1.4108x over previous
//
#include <hip/hip_runtime.h>
#include <math.h>

#define NFFT     1024
#define HOP      256
#define NFRAMES  622
#define NBATCH   32
#define XLEN     160000
#define TILE_T   16
#define NPAIR    8
#define ROW      1153      // 1024 + 2*64 pad + 1 stagger (==1 mod 16)
#define KBINS    513
#define NT       512
#define NTILES   39        // ceil(622/16)
#define NBLK     (NTILES*NBATCH)   // 1248 = 8*156 exactly

// pad 2 slots every 16 complex: keeps float4 (b128) pairs aligned+contiguous,
// and makes stride-64 / stride-16 / stride-1 / contiguous-b128 accesses all
// hit each bank-pair exactly 4x (verified per-pattern).
#define ZIDX(j,i) ((j)*ROW + (i) + 2*((i)>>4))
// tw pad every 16: makes tw[4c] / tw[16m] reads conflict-free
#define TWIDX(e)  ((e) + ((e)>>4))

#define C1 0.9238795325112867f   // cos(pi/8)
#define S1 0.3826834323650898f   // sin(pi/8)
#define C2 0.7071067811865476f   // cos(pi/4)

__device__ __forceinline__ float2 cmul(float2 a, float2 b) {
    return make_float2(a.x*b.x - a.y*b.y, a.x*b.y + a.y*b.x);
}
__device__ __forceinline__ float2 csqr(float2 a) {
    return make_float2(a.x*a.x - a.y*a.y, 2.0f*a.x*a.y);
}

// radix-4 DIF butterfly; b,c,d get twiddled outputs (positions +M,+2M,+3M)
__device__ __forceinline__ void bfly4(float2& a, float2& b, float2& c, float2& d,
                                      float2 w1, float2 w2, float2 w3) {
    float2 apc = make_float2(a.x + c.x, a.y + c.y);
    float2 amc = make_float2(a.x - c.x, a.y - c.y);
    float2 bpd = make_float2(b.x + d.x, b.y + d.y);
    float2 bmd = make_float2(b.x - d.x, b.y - d.y);
    float2 y0 = make_float2(apc.x + bpd.x, apc.y + bpd.y);
    float2 y2 = make_float2(apc.x - bpd.x, apc.y - bpd.y);
    float2 y1 = make_float2(amc.x + bmd.y, amc.y - bmd.x);  // amc - i*bmd
    float2 y3 = make_float2(amc.x - bmd.y, amc.y + bmd.x);  // amc + i*bmd
    a = y0; b = cmul(w1, y1); c = cmul(w2, y2); d = cmul(w3, y3);
}
__device__ __forceinline__ void bfly4_nw(float2& a, float2& b, float2& c, float2& d) {
    float2 apc = make_float2(a.x + c.x, a.y + c.y);
    float2 amc = make_float2(a.x - c.x, a.y - c.y);
    float2 bpd = make_float2(b.x + d.x, b.y + d.y);
    float2 bmd = make_float2(b.x - d.x, b.y - d.y);
    a = make_float2(apc.x + bpd.x, apc.y + bpd.y);
    b = make_float2(amc.x + bmd.y, amc.y - bmd.x);
    c = make_float2(apc.x - bpd.x, apc.y - bpd.y);
    d = make_float2(amc.x - bmd.y, amc.y + bmd.x);
}

__device__ __forceinline__ int rev4(int k) {
    return ((k & 3) << 8) | ((k & 12) << 4) | (k & 48) | ((k >> 4) & 12) | ((k >> 8) & 3);
}

// wave-internal LDS ordering fence (HW keeps a wave's DS ops in order; this
// pins the compiler). Rule #18: sched_barrier after the inline-asm waitcnt.
__device__ __forceinline__ void fence() {
    asm volatile("s_waitcnt lgkmcnt(0)" ::: "memory");
    __builtin_amdgcn_sched_barrier(0);
}

__global__ __launch_bounds__(NT, 4)
void spec_kernel(const float* __restrict__ x, const float* __restrict__ win,
                 float* __restrict__ out)
{
    __shared__ __align__(16) float2 zb[NPAIR * ROW];  // 73,792 B
    __shared__ float2 tw[816];                        //  6,528 B -> 80,320 total

    const int tid = threadIdx.x;
    // chunked bijective XCD swizzle: hw-bid round-robins over 8 XCDs; give
    // each XCD a contiguous run of logical ids so adjacent t-tiles share L2.
    const int lg = (blockIdx.x & 7) * (NBLK / 8) + (blockIdx.x >> 3);
    const int b  = lg / NTILES;
    const int t0 = (lg % NTILES) * TILE_T;
    const int wv = tid >> 6;     // wave id == packed-array id
    const int l  = tid & 63;

    // ---- twiddle table (f64 accuracy), padded layout ----
    for (int e = tid; e < 768; e += NT) {
        double ang = -6.283185307179586476925286766559 * ((double)e / 1024.0);
        tw[TWIDX(e)] = make_float2((float)cos(ang), (float)sin(ang));
    }

    // ---- wave-local load + window: frames (2wv, 2wv+1) -> complex array wv ----
    {
        const int f0 = t0 + 2*wv, f1 = f0 + 1;   // wave-uniform
        const float* xb = x + (size_t)b * XLEN;
        #pragma unroll
        for (int q = 0; q < 16; ++q) {
            const int n = (q << 6) + l;
            const float wn = win[n];             // real_w row 0 == fp32 hanning
            float x0 = (f0 < NFRAMES) ? xb[f0*HOP + n] : 0.0f;
            float x1 = (f1 < NFRAMES) ? xb[f1*HOP + n] : 0.0f;
            zb[ZIDX(wv, n)] = make_float2(wn*x0, wn*x1);
        }
    }
    __syncthreads();   // publishes tw[] (zb is wave-local)

    // ---- fused stages 0+1 (radix-16 in registers): lane c holds z[64j+c] ----
    {
        const int c = l;
        float2 E[16];
        #pragma unroll
        for (int j = 0; j < 16; ++j) E[j] = zb[ZIDX(wv, (j << 6) + c)];
        // stage 0: butterflies {m, m+256, m+512, m+768}, m = c + 64q
        const float2 wc = tw[TWIDX(c)];
        #pragma unroll
        for (int q = 0; q < 4; ++q) {
            float2 w1;
            if      (q == 0) w1 = wc;
            else if (q == 1) w1 = cmul(wc, make_float2(C1, -S1));   // W16^1
            else if (q == 2) w1 = cmul(wc, make_float2(C2, -C2));   // W16^2
            else             w1 = cmul(wc, make_float2(S1, -C1));   // W16^3
            float2 w2 = csqr(w1);
            float2 w3 = cmul(w1, w2);
            bfly4(E[q], E[q+4], E[q+8], E[q+12], w1, w2, w3);
        }
        // stage 1: within each 256-block, twiddle W_1024^{4c}
        const float2 wb  = tw[TWIDX(4*c)];
        const float2 wb2 = csqr(wb);
        const float2 wb3 = cmul(wb, wb2);
        #pragma unroll
        for (int u = 0; u < 4; ++u)
            bfly4(E[4*u], E[4*u+1], E[4*u+2], E[4*u+3], wb, wb2, wb3);
        #pragma unroll
        for (int j = 0; j < 16; ++j) zb[ZIDX(wv, (j << 6) + c)] = E[j];
        fence();
    }

    // ---- stage 2 (M=16, S=16), twiddle hoisted (depends only on l&15) ----
    {
        const int m = l & 15;
        const int h = l >> 4;
        const float2 w1 = tw[TWIDX(16*m)];
        const float2 w2 = csqr(w1);
        const float2 w3 = cmul(w1, w2);
        #pragma unroll
        for (int u = 0; u < 4; ++u) {
            const int base = 256*u + 64*h + m;
            float2 a  = zb[ZIDX(wv, base)];
            float2 bb = zb[ZIDX(wv, base + 16)];
            float2 cc = zb[ZIDX(wv, base + 32)];
            float2 dd = zb[ZIDX(wv, base + 48)];
            bfly4(a, bb, cc, dd, w1, w2, w3);
            zb[ZIDX(wv, base)]      = a;
            zb[ZIDX(wv, base + 16)] = bb;
            zb[ZIDX(wv, base + 32)] = cc;
            zb[ZIDX(wv, base + 48)] = dd;
        }
        fence();
    }

    // ---- fused stages 3+4 (radix-16 in registers, constant twiddles) ----
    {
        float2 F[16];
        #pragma unroll
        for (int r = 0; r < 8; ++r) {
            const float4 v = *reinterpret_cast<const float4*>(&zb[ZIDX(wv, 16*l + 2*r)]);
            F[2*r]   = make_float2(v.x, v.y);
            F[2*r+1] = make_float2(v.z, v.w);
        }
        // stage 3: {m, m+4, m+8, m+12}, twiddles W16^{m,2m,3m}
        bfly4_nw(F[0], F[4], F[8],  F[12]);
        bfly4(F[1], F[5], F[9],  F[13], make_float2(C1,-S1), make_float2(C2,-C2), make_float2(S1,-C1));
        bfly4(F[2], F[6], F[10], F[14], make_float2(C2,-C2), make_float2(0.f,-1.f), make_float2(-C2,-C2));
        bfly4(F[3], F[7], F[11], F[15], make_float2(S1,-C1), make_float2(-C2,-C2), make_float2(-C1, S1));
        // stage 4: {4p..4p+3}, no twiddles
        bfly4_nw(F[0],  F[1],  F[2],  F[3]);
        bfly4_nw(F[4],  F[5],  F[6],  F[7]);
        bfly4_nw(F[8],  F[9],  F[10], F[11]);
        bfly4_nw(F[12], F[13], F[14], F[15]);
        #pragma unroll
        for (int r = 0; r < 8; ++r) {
            *reinterpret_cast<float4*>(&zb[ZIDX(wv, 16*l + 2*r)]) =
                make_float4(F[2*r].x, F[2*r].y, F[2*r+1].x, F[2*r+1].y);
        }
    }
    __syncthreads();   // publish all arrays for the cross-wave output phase

    // ---- unpack + mag/phase; each lane does one frame-PAIR -> float2 stores ----
    const int kg = tid >> 3;          // 0..63
    const int jj = tid & 7;           // array == frame pair
    const int t_e = t0 + 2*jj;        // frames come in (even, odd) pairs
    const bool tval = (t_e < NFRAMES);   // pair-valid (NFRAMES even)

    float* magp = out;                                        // [32][513][622]
    float* php  = out + (size_t)NBATCH * KBINS * NFRAMES;     // [32][1024][622]
    const size_t magbase = (size_t)b * KBINS * NFRAMES + t_e;
    const size_t phbase  = (size_t)b * NFFT  * NFRAMES + t_e;

    #pragma unroll 2
    for (int it = 0; it < 9; ++it) {
        const int k = kg + (it << 6);
        if (it == 8 && kg != 0) break;          // only k=512 remains
        const int r1 = rev4(k);
        const int r2 = rev4((NFFT - k) & (NFFT - 1));
        const float2 z1 = zb[ZIDX(jj, r1)];
        const float2 z2 = zb[ZIDX(jj, r2)];
        // F_even[k] = (Z[k]+conj(Z[N-k]))/2 ; F_odd[k] = -i(Z[k]-conj(Z[N-k]))/2
        const float re_e = 0.5f*(z1.x + z2.x);
        const float im_e = 0.5f*(z1.y - z2.y);   // exact +0.0 at k=0,512
        const float re_o = 0.5f*(z1.y + z2.y);
        const float im_o = 0.5f*(z2.x - z1.x);
        if (tval) {
            *reinterpret_cast<float2*>(&magp[magbase + (size_t)k * NFRAMES]) =
                make_float2(re_e*re_e + im_e*im_e, re_o*re_o + im_o*im_o);
            const float ph_e = atan2f(im_e, re_e);
            const float ph_o = atan2f(im_o, re_o);
            *reinterpret_cast<float2*>(&php[phbase + (size_t)k * NFRAMES]) =
                make_float2(ph_e, ph_o);
            if (k != 0 && k != 512) {           // mirror bins: conj symmetry
                const float pm_e = (im_e != 0.0f) ? -ph_e : atan2f(-im_e, re_e);
                const float pm_o = (im_o != 0.0f) ? -ph_o : atan2f(-im_o, re_o);
                *reinterpret_cast<float2*>(&php[phbase + (size_t)(NFFT - k) * NFRAMES]) =
                    make_float2(pm_e, pm_o);
            }
        }
    }
}

extern "C" void kernel_launch(void* const* d_in, const int* in_sizes, int n_in,
                              void* d_out, int out_size, void* d_ws, size_t ws_size,
                              hipStream_t stream) {
    const float* x  = (const float*)d_in[0];
    const float* rw = (const float*)d_in[1];   // row 0 = fp32 hanning window
    float* out = (float*)d_out;
    spec_kernel<<<dim3(NBLK, 1, 1), dim3(NT, 1, 1), 0, stream>>>(x, rw, out);
}

// Round 4
// 43.187 us; speedup vs baseline: 2.0277x; 1.2048x over previous
//
#include <hip/hip_runtime.h>
#include <math.h>

#define NFFT     1024
#define HOP      256
#define NFRAMES  622
#define NBATCH   32
#define XLEN     160000
#define TILE_T   8
#define NPAIR    4
#define ROW      1234      // max padded index 1233 (+1); even; ==2 mod 16 (row stagger)
#define KBINS    513
#define NT       256
#define NTILES   78        // ceil(622/8)
#define NBLK     (NTILES*NBATCH)   // 2496 = 8*312 exactly (bijective XCD swizzle)

// multi-digit pad: spreads base-4 digits d1..d4 into the bank-pair index.
// Verified per access pattern: load/b128 stores 2-way, stage01 stride-64 reads
// conflict-free, stage2 stride-16 conflict-free, stage34 b128 2-way,
// output rev4-reads ~2-way. (2-way is free on CDNA4.)
#define ZIDX(j,i) ((j)*ROW + (i) + 2*((i)>>4) + 4*((i)>>6) + 8*((i)>>8))

#define C1 0.9238795325112867f   // cos(pi/8)
#define S1 0.3826834323650898f   // sin(pi/8)
#define C2 0.7071067811865476f   // cos(pi/4)
#define STEP (-0.006135923151542565f)   // -2*pi/1024

__device__ __forceinline__ float2 cmul(float2 a, float2 b) {
    return make_float2(a.x*b.x - a.y*b.y, a.x*b.y + a.y*b.x);
}
__device__ __forceinline__ float2 csqr(float2 a) {
    return make_float2(a.x*a.x - a.y*a.y, 2.0f*a.x*a.y);
}

__device__ __forceinline__ void bfly4(float2& a, float2& b, float2& c, float2& d,
                                      float2 w1, float2 w2, float2 w3) {
    float2 apc = make_float2(a.x + c.x, a.y + c.y);
    float2 amc = make_float2(a.x - c.x, a.y - c.y);
    float2 bpd = make_float2(b.x + d.x, b.y + d.y);
    float2 bmd = make_float2(b.x - d.x, b.y - d.y);
    float2 y0 = make_float2(apc.x + bpd.x, apc.y + bpd.y);
    float2 y2 = make_float2(apc.x - bpd.x, apc.y - bpd.y);
    float2 y1 = make_float2(amc.x + bmd.y, amc.y - bmd.x);  // amc - i*bmd
    float2 y3 = make_float2(amc.x - bmd.y, amc.y + bmd.x);  // amc + i*bmd
    a = y0; b = cmul(w1, y1); c = cmul(w2, y2); d = cmul(w3, y3);
}
__device__ __forceinline__ void bfly4_nw(float2& a, float2& b, float2& c, float2& d) {
    float2 apc = make_float2(a.x + c.x, a.y + c.y);
    float2 amc = make_float2(a.x - c.x, a.y - c.y);
    float2 bpd = make_float2(b.x + d.x, b.y + d.y);
    float2 bmd = make_float2(b.x - d.x, b.y - d.y);
    a = make_float2(apc.x + bpd.x, apc.y + bpd.y);
    b = make_float2(amc.x + bmd.y, amc.y - bmd.x);
    c = make_float2(apc.x - bpd.x, apc.y - bpd.y);
    d = make_float2(amc.x - bmd.y, amc.y + bmd.x);
}

__device__ __forceinline__ int rev4(int k) {
    return ((k & 3) << 8) | ((k & 12) << 4) | (k & 48) | ((k >> 4) & 12) | ((k >> 8) & 3);
}

// wave-internal LDS ordering fence (HW keeps a wave's DS ops in order; this
// pins the compiler; rule #18: sched_barrier after the inline-asm waitcnt).
__device__ __forceinline__ void fence() {
    asm volatile("s_waitcnt lgkmcnt(0)" ::: "memory");
    __builtin_amdgcn_sched_barrier(0);
}

// ~20-instr atan2: minimax deg-11 odd poly on [0,1], max err ~5e-6 rad.
// IEEE-consistent signed zeros via copysign: atan2(+-0, x>0) = +-0,
// atan2(+-0, x<0) = +-pi, atan2(0,0) handled by the mx==0 guard.
__device__ __forceinline__ float fast_atan2f(float y, float x) {
    const float ax = fabsf(x), ay = fabsf(y);
    const float mx = fmaxf(ax, ay), mn = fminf(ax, ay);
    float r = mn / mx;
    if (mx == 0.0f) r = 0.0f;
    const float t = r * r;
    float p = fmaf(t, -0.01172120f, 0.05265332f);
    p = fmaf(t, p, -0.11643287f);
    p = fmaf(t, p, 0.19354346f);
    p = fmaf(t, p, -0.33262347f);
    p = fmaf(t, p, 0.99997726f);
    float a = r * p;
    a = (ay > ax) ? (1.5707963267948966f - a) : a;
    a = (x < 0.0f) ? (3.14159265358979323f - a) : a;
    return copysignf(a, y);
}

__global__ __launch_bounds__(NT, 4)
void spec_kernel(const float* __restrict__ x, const float* __restrict__ win,
                 float* __restrict__ out)
{
    __shared__ __align__(16) float2 zb[NPAIR * ROW];  // 39,488 B -> 4 blocks/CU

    const int tid = threadIdx.x;
    const int lg  = (blockIdx.x & 7) * (NBLK / 8) + (blockIdx.x >> 3);
    const int b   = lg / NTILES;
    const int t0  = (lg - b * NTILES) * TILE_T;
    const int wv  = tid >> 6;     // wave id == packed-array id
    const int ln  = tid & 63;

    // ---- wave-local vectorized load + window: frames (2wv,2wv+1) -> array wv ----
    {
        const int f0 = t0 + 2*wv, f1 = f0 + 1;       // wave-uniform
        const float* xb = x + (size_t)b * XLEN;
        const bool v0 = (f0 < NFRAMES), v1 = (f1 < NFRAMES);
        #pragma unroll
        for (int q = 0; q < 4; ++q) {
            const int n0 = (q << 8) + (ln << 2);
            const float4 w4 = *reinterpret_cast<const float4*>(&win[n0]);
            float4 a4 = make_float4(0.f, 0.f, 0.f, 0.f), b4 = a4;
            if (v0) a4 = *reinterpret_cast<const float4*>(&xb[f0*HOP + n0]);
            if (v1) b4 = *reinterpret_cast<const float4*>(&xb[f1*HOP + n0]);
            float4* dst = reinterpret_cast<float4*>(&zb[ZIDX(wv, n0)]);
            dst[0] = make_float4(w4.x*a4.x, w4.x*b4.x, w4.y*a4.y, w4.y*b4.y);
            dst[1] = make_float4(w4.z*a4.z, w4.z*b4.z, w4.w*a4.w, w4.w*b4.w);
        }
    }
    fence();

    // ---- fused stages 0+1 (radix-16 in registers); twiddles on the fly ----
    {
        float2 E[16];
        #pragma unroll
        for (int j = 0; j < 16; ++j) E[j] = zb[ZIDX(wv, (j << 6) + ln)];
        float sw, cw;
        sincosf(STEP * (float)ln, &sw, &cw);
        const float2 wc = make_float2(cw, sw);          // W_1024^ln
        #pragma unroll
        for (int q = 0; q < 4; ++q) {
            float2 w1;
            if      (q == 0) w1 = wc;
            else if (q == 1) w1 = cmul(wc, make_float2(C1, -S1));   // *W16^1
            else if (q == 2) w1 = cmul(wc, make_float2(C2, -C2));   // *W16^2
            else             w1 = cmul(wc, make_float2(S1, -C1));   // *W16^3
            float2 w2 = csqr(w1), w3 = cmul(w1, w2);
            bfly4(E[q], E[q+4], E[q+8], E[q+12], w1, w2, w3);
        }
        const float2 wb  = csqr(csqr(wc));              // W_1024^{4ln}
        const float2 wb2 = csqr(wb), wb3 = cmul(wb, wb2);
        #pragma unroll
        for (int u = 0; u < 4; ++u)
            bfly4(E[4*u], E[4*u+1], E[4*u+2], E[4*u+3], wb, wb2, wb3);
        #pragma unroll
        for (int j = 0; j < 16; ++j) zb[ZIDX(wv, (j << 6) + ln)] = E[j];
    }
    fence();

    // ---- stage 2 (M=16), twiddle W_1024^{16m} on the fly ----
    {
        const int m = ln & 15, h = ln >> 4;
        float sm, cm;
        sincosf((STEP * 16.0f) * (float)m, &sm, &cm);
        const float2 w1 = make_float2(cm, sm);
        const float2 w2 = csqr(w1), w3 = cmul(w1, w2);
        #pragma unroll
        for (int u = 0; u < 4; ++u) {
            const int base = 256*u + 64*h + m;
            float2 a  = zb[ZIDX(wv, base)],      bb = zb[ZIDX(wv, base + 16)];
            float2 cc = zb[ZIDX(wv, base + 32)], dd = zb[ZIDX(wv, base + 48)];
            bfly4(a, bb, cc, dd, w1, w2, w3);
            zb[ZIDX(wv, base)]      = a;  zb[ZIDX(wv, base + 16)] = bb;
            zb[ZIDX(wv, base + 32)] = cc; zb[ZIDX(wv, base + 48)] = dd;
        }
    }
    fence();

    // ---- fused stages 3+4 (registers, constant twiddles), b128 LDS traffic ----
    {
        float2 F[16];
        const float4* src = reinterpret_cast<const float4*>(&zb[ZIDX(wv, ln << 4)]);
        #pragma unroll
        for (int r = 0; r < 8; ++r) {
            const float4 v = src[r];
            F[2*r]   = make_float2(v.x, v.y);
            F[2*r+1] = make_float2(v.z, v.w);
        }
        bfly4_nw(F[0], F[4], F[8],  F[12]);
        bfly4(F[1], F[5], F[9],  F[13], make_float2(C1,-S1), make_float2(C2,-C2), make_float2(S1,-C1));
        bfly4(F[2], F[6], F[10], F[14], make_float2(C2,-C2), make_float2(0.f,-1.f), make_float2(-C2,-C2));
        bfly4(F[3], F[7], F[11], F[15], make_float2(S1,-C1), make_float2(-C2,-C2), make_float2(-C1, S1));
        bfly4_nw(F[0],  F[1],  F[2],  F[3]);
        bfly4_nw(F[4],  F[5],  F[6],  F[7]);
        bfly4_nw(F[8],  F[9],  F[10], F[11]);
        bfly4_nw(F[12], F[13], F[14], F[15]);
        float4* dst = reinterpret_cast<float4*>(&zb[ZIDX(wv, ln << 4)]);
        #pragma unroll
        for (int r = 0; r < 8; ++r)
            dst[r] = make_float4(F[2*r].x, F[2*r].y, F[2*r+1].x, F[2*r+1].y);
    }
    __syncthreads();   // the only block barrier: publish arrays for output phase

    // ---- unpack + mag/phase; lane = (k-group, frame-pair); float2 stores ----
    const int kg  = tid >> 2;          // 0..63
    const int jj  = tid & 3;           // array == frame pair
    const int t_e = t0 + 2*jj;
    const bool tval = (t_e < NFRAMES); // pair-valid (NFRAMES even)

    // rev4(kg + 64it) = rev4(kg) + rev4(64it): digit-disjoint. Same for the
    // conjugate index: 1024-k = (64-kg) + 64*j2, j2 = (J0-it)&15, J0=16 iff kg==0.
    const int R1 = rev4(kg);                           // multiple of 16
    const int km = 64 - kg;
    const int R2 = ((km & 3) << 8) | ((km & 12) << 4) | (km & 48);  // ==0 for kg==0
    const int J0 = (kg == 0) ? 16 : 15;
    const float2* zp1 = &zb[ZIDX(jj, R1)];   // +c(it) stays inside the 16-block
    const float2* zp2 = &zb[ZIDX(jj, R2)];

    float* magp = out;                                        // [32][513][622]
    float* php  = out + (size_t)NBATCH * KBINS * NFRAMES;     // [32][1024][622]
    const size_t magbase = (size_t)b * KBINS * NFRAMES + t_e;
    const size_t phbase  = (size_t)b * NFFT  * NFRAMES + t_e;

    #pragma unroll
    for (int it = 0; it < 9; ++it) {
        if (it == 8 && kg != 0) break;             // only k=512 remains
        const int k  = kg + (it << 6);
        const int c1 = ((it & 3) << 2) | (it >> 2);            // rev4(64it), imm
        const int j2 = (J0 - it) & 15;
        const int c2 = ((j2 & 3) << 2) | (j2 >> 2);
        const float2 z1 = zp1[c1];
        const float2 z2 = zp2[c2];
        // F_even[k] = (Z[k]+conj(Z[N-k]))/2 ; F_odd[k] = -i(Z[k]-conj(Z[N-k]))/2
        const float re_e = 0.5f*(z1.x + z2.x);
        const float im_e = 0.5f*(z1.y - z2.y);     // exact +0.0 at k=0,512
        const float re_o = 0.5f*(z1.y + z2.y);
        const float im_o = 0.5f*(z2.x - z1.x);
        if (tval) {
            *reinterpret_cast<float2*>(&magp[magbase + (size_t)k * NFRAMES]) =
                make_float2(fmaf(re_e, re_e, im_e*im_e), fmaf(re_o, re_o, im_o*im_o));
            const float ph_e = fast_atan2f(im_e, re_e);
            const float ph_o = fast_atan2f(im_o, re_o);
            *reinterpret_cast<float2*>(&php[phbase + (size_t)k * NFRAMES]) =
                make_float2(ph_e, ph_o);
            if (k != 0 && k != 512) {
                // atan2 is odd in y INCLUDING signed zeros -> mirror = sign flip
                *reinterpret_cast<float2*>(&php[phbase + (size_t)(NFFT - k) * NFRAMES]) =
                    make_float2(-ph_e, -ph_o);
            }
        }
    }
}

extern "C" void kernel_launch(void* const* d_in, const int* in_sizes, int n_in,
                              void* d_out, int out_size, void* d_ws, size_t ws_size,
                              hipStream_t stream) {
    const float* x  = (const float*)d_in[0];
    const float* rw = (const float*)d_in[1];   // row 0 = fp32 hanning window
    float* out = (float*)d_out;
    spec_kernel<<<dim3(NBLK, 1, 1), dim3(NT, 1, 1), 0, stream>>>(x, rw, out);
}

// Round 5
// 40.268 us; speedup vs baseline: 2.1747x; 1.0725x over previous
//
#include <hip/hip_runtime.h>
#include <math.h>

#define NFFT     1024
#define HOP      256
#define NFRAMES  622
#define NBATCH   32
#define XLEN     160000
#define TILE_T   16
#define NPAIR    8
#define ROW      1234      // padded float2 stride per array; 1234 mod 16 = 2
#define KBINS    513
#define NT       512
#define NTILES   39        // ceil(622/16)
#define NBLK     (NTILES*NBATCH)   // 1248 = 8*156 exactly (bijective XCD swizzle)

// multi-digit pad (float2 units). All per-phase accesses below use closed-form
// folded offsets derived from this: PAD(i) = i + 2(i>>4) + 4(i>>6) + 8(i>>8).
#define PAD(i)   ((i) + 2*((i)>>4) + 4*((i)>>6) + 8*((i)>>8))

#define C1 0.9238795325112867f   // cos(pi/8)
#define S1 0.3826834323650898f   // sin(pi/8)
#define C2 0.7071067811865476f   // cos(pi/4)

__device__ __forceinline__ float2 cmul(float2 a, float2 b) {
    return make_float2(a.x*b.x - a.y*b.y, a.x*b.y + a.y*b.x);
}
__device__ __forceinline__ float2 csqr(float2 a) {
    return make_float2(a.x*a.x - a.y*a.y, 2.0f*a.x*a.y);
}

// hardware sin/cos: input in REVOLUTIONS (sin(2*pi*f)); args here are < 0.25
// in magnitude so no range reduction is needed. ~1e-6 abs accuracy.
__device__ __forceinline__ float2 w_of_rev(float f) {
    float s, c;
    asm("v_sin_f32 %0, %1" : "=v"(s) : "v"(f));
    asm("v_cos_f32 %0, %1" : "=v"(c) : "v"(f));
    return make_float2(c, s);
}

__device__ __forceinline__ void bfly4(float2& a, float2& b, float2& c, float2& d,
                                      float2 w1, float2 w2, float2 w3) {
    float2 apc = make_float2(a.x + c.x, a.y + c.y);
    float2 amc = make_float2(a.x - c.x, a.y - c.y);
    float2 bpd = make_float2(b.x + d.x, b.y + d.y);
    float2 bmd = make_float2(b.x - d.x, b.y - d.y);
    float2 y0 = make_float2(apc.x + bpd.x, apc.y + bpd.y);
    float2 y2 = make_float2(apc.x - bpd.x, apc.y - bpd.y);
    float2 y1 = make_float2(amc.x + bmd.y, amc.y - bmd.x);  // amc - i*bmd
    float2 y3 = make_float2(amc.x - bmd.y, amc.y + bmd.x);  // amc + i*bmd
    a = y0; b = cmul(w1, y1); c = cmul(w2, y2); d = cmul(w3, y3);
}
__device__ __forceinline__ void bfly4_nw(float2& a, float2& b, float2& c, float2& d) {
    float2 apc = make_float2(a.x + c.x, a.y + c.y);
    float2 amc = make_float2(a.x - c.x, a.y - c.y);
    float2 bpd = make_float2(b.x + d.x, b.y + d.y);
    float2 bmd = make_float2(b.x - d.x, b.y - d.y);
    a = make_float2(apc.x + bpd.x, apc.y + bpd.y);
    b = make_float2(amc.x + bmd.y, amc.y - bmd.x);
    c = make_float2(apc.x - bpd.x, apc.y - bpd.y);
    d = make_float2(amc.x - bmd.y, amc.y + bmd.x);
}

// wave-internal LDS ordering fence (HW keeps a wave's DS ops in order; this
// pins the compiler; rule #18: sched_barrier after the inline-asm waitcnt).
__device__ __forceinline__ void fence() {
    asm volatile("s_waitcnt lgkmcnt(0)" ::: "memory");
    __builtin_amdgcn_sched_barrier(0);
}

// ~17-instr atan2: raw v_rcp (1 ulp) + deg-11 minimax odd poly, err ~5e-6 rad.
// Signed-zero-correct via copysign; mx==0 guard handles atan2(0,0).
__device__ __forceinline__ float fast_atan2f(float y, float x) {
    const float ax = fabsf(x), ay = fabsf(y);
    const float mx = fmaxf(ax, ay), mn = fminf(ax, ay);
    float r = mn * __builtin_amdgcn_rcpf(mx);
    if (mx == 0.0f) r = 0.0f;
    const float t = r * r;
    float p = fmaf(t, -0.01172120f, 0.05265332f);
    p = fmaf(t, p, -0.11643287f);
    p = fmaf(t, p, 0.19354346f);
    p = fmaf(t, p, -0.33262347f);
    p = fmaf(t, p, 0.99997726f);
    float a = r * p;
    a = (ay > ax) ? (1.5707963267948966f - a) : a;
    a = (x < 0.0f) ? (3.14159265358979323f - a) : a;
    return copysignf(a, y);
}

__global__ __launch_bounds__(NT, 4)
void spec_kernel(const float* __restrict__ x, const float* __restrict__ win,
                 float* __restrict__ out)
{
    __shared__ __align__(16) float2 zb[NPAIR * ROW];  // 78,976 B -> 2 blocks/CU

    const int tid = threadIdx.x;
    const int lg  = (blockIdx.x & 7) * (NBLK / 8) + (blockIdx.x >> 3);
    const int b   = lg / NTILES;
    const int t0  = (lg - b * NTILES) * TILE_T;
    const int wv  = tid >> 6;     // wave id == packed-array id
    const int ln  = tid & 63;

    // ---- wave-local vectorized load + window: frames (2wv,2wv+1) -> array wv ----
    // PAD(256q + 4ln) = PAD(4ln) + 312q  (float2)  ->  float4 offsets 156q.
    {
        const int f0 = t0 + 2*wv, f1 = f0 + 1;       // wave-uniform
        const float* xb = x + (size_t)b * XLEN;
        const bool v0 = (f0 < NFRAMES), v1 = (f1 < NFRAMES);
        float4* D4 = reinterpret_cast<float4*>(
            &zb[wv*ROW + 4*ln + 2*(ln>>2) + 4*(ln>>4)]);
        #pragma unroll
        for (int q = 0; q < 4; ++q) {
            const int n0 = (q << 8) + (ln << 2);
            const float4 w4 = *reinterpret_cast<const float4*>(&win[n0]);
            float4 a4 = make_float4(0.f, 0.f, 0.f, 0.f), b4 = a4;
            if (v0) a4 = *reinterpret_cast<const float4*>(&xb[f0*HOP + n0]);
            if (v1) b4 = *reinterpret_cast<const float4*>(&xb[f1*HOP + n0]);
            D4[156*q]     = make_float4(w4.x*a4.x, w4.x*b4.x, w4.y*a4.y, w4.y*b4.y);
            D4[156*q + 1] = make_float4(w4.z*a4.z, w4.z*b4.z, w4.w*a4.w, w4.w*b4.w);
        }
    }
    fence();

    // ---- fused stages 0+1 (radix-16 in registers); HW-trans twiddles ----
    // PAD(64j + ln) = PAD(ln) + 76j + 8(j>>2): single base + const offsets.
    {
        float2* p = &zb[wv*ROW + ln + 2*(ln>>4)];
        float2 E[16];
        #pragma unroll
        for (int j = 0; j < 16; ++j) E[j] = p[76*j + 8*(j>>2)];
        const float2 wc = w_of_rev((float)ln * (-1.0f/1024.0f));   // W_1024^ln
        #pragma unroll
        for (int q = 0; q < 4; ++q) {
            float2 w1;
            if      (q == 0) w1 = wc;
            else if (q == 1) w1 = cmul(wc, make_float2(C1, -S1));   // *W16^1
            else if (q == 2) w1 = cmul(wc, make_float2(C2, -C2));   // *W16^2
            else             w1 = cmul(wc, make_float2(S1, -C1));   // *W16^3
            float2 w2 = csqr(w1), w3 = cmul(w1, w2);
            bfly4(E[q], E[q+4], E[q+8], E[q+12], w1, w2, w3);
        }
        const float2 wb  = w_of_rev((float)ln * (-4.0f/1024.0f));  // W_1024^{4ln}
        const float2 wb2 = csqr(wb), wb3 = cmul(wb, wb2);
        #pragma unroll
        for (int u = 0; u < 4; ++u)
            bfly4(E[4*u], E[4*u+1], E[4*u+2], E[4*u+3], wb, wb2, wb3);
        #pragma unroll
        for (int j = 0; j < 16; ++j) p[76*j + 8*(j>>2)] = E[j];
    }
    fence();

    // ---- stage 2 (M=16): PAD(256u + 64h + 16s + m) = PAD-base + 312u + 18s ----
    {
        const int m = ln & 15, h = ln >> 4;
        float2* p = &zb[wv*ROW + 76*h + m];
        const float2 w1 = w_of_rev((float)m * (-1.0f/64.0f));      // W_64^m
        const float2 w2 = csqr(w1), w3 = cmul(w1, w2);
        #pragma unroll
        for (int u = 0; u < 4; ++u) {
            float2 a  = p[312*u],      bb = p[312*u + 18];
            float2 cc = p[312*u + 36], dd = p[312*u + 54];
            bfly4(a, bb, cc, dd, w1, w2, w3);
            p[312*u]      = a;  p[312*u + 18] = bb;
            p[312*u + 36] = cc; p[312*u + 54] = dd;
        }
    }
    fence();

    // ---- fused stages 3+4 (registers, constant twiddles), b128 LDS traffic ----
    // PAD(16ln + 2r) = 18ln + 4(ln>>2) + 8(ln>>4) + 2r -> float4 offsets r.
    {
        float4* p = reinterpret_cast<float4*>(
            &zb[wv*ROW + 18*ln + 4*(ln>>2) + 8*(ln>>4)]);
        float2 F[16];
        #pragma unroll
        for (int r = 0; r < 8; ++r) {
            const float4 v = p[r];
            F[2*r]   = make_float2(v.x, v.y);
            F[2*r+1] = make_float2(v.z, v.w);
        }
        bfly4_nw(F[0], F[4], F[8],  F[12]);
        bfly4(F[1], F[5], F[9],  F[13], make_float2(C1,-S1), make_float2(C2,-C2), make_float2(S1,-C1));
        bfly4(F[2], F[6], F[10], F[14], make_float2(C2,-C2), make_float2(0.f,-1.f), make_float2(-C2,-C2));
        bfly4(F[3], F[7], F[11], F[15], make_float2(S1,-C1), make_float2(-C2,-C2), make_float2(-C1, S1));
        bfly4_nw(F[0],  F[1],  F[2],  F[3]);
        bfly4_nw(F[4],  F[5],  F[6],  F[7]);
        bfly4_nw(F[8],  F[9],  F[10], F[11]);
        bfly4_nw(F[12], F[13], F[14], F[15]);
        #pragma unroll
        for (int r = 0; r < 8; ++r)
            p[r] = make_float4(F[2*r].x, F[2*r].y, F[2*r+1].x, F[2*r+1].y);
    }
    __syncthreads();   // the only block barrier: publish arrays for output phase

    // ---- unpack + mag/phase; lane = (k-group, frame-pair); 64-B write runs ----
    const int kg  = tid >> 3;          // 0..63
    const int jj  = tid & 7;           // array == frame pair
    const int t_e = t0 + 2*jj;
    const bool tval = (t_e < NFRAMES); // pair-valid (NFRAMES even)

    // rev4(kg + 64it) = rev4(kg) + rev4(64it) (digit-disjoint); conj index
    // 1024-k = (64-kg) + 64*j2, j2 = (J0-it)&15, J0=16 iff kg==0. Both R1,R2
    // are multiples of 16, so PAD(R+c) = PAD(R)+c for c<16.
    const int R1 = ((kg & 3) << 8) | ((kg & 12) << 4) | (kg & 48);
    const int km = 64 - kg;
    const int R2 = ((km & 3) << 8) | ((km & 12) << 4) | (km & 48);
    const int J0 = (kg == 0) ? 16 : 15;
    const float2* zp1 = &zb[jj*ROW + PAD(R1)];
    const float2* zp2 = &zb[jj*ROW + PAD(R2)];

    float* magp = out;                                        // [32][513][622]
    float* php  = out + (size_t)NBATCH * KBINS * NFRAMES;     // [32][1024][622]
    const size_t magbase = (size_t)b * KBINS * NFRAMES + t_e;
    const size_t phbase  = (size_t)b * NFFT  * NFRAMES + t_e;

    if (tval) {
        #pragma unroll
        for (int it = 0; it < 9; ++it) {
            if (it == 8 && kg != 0) break;             // only k=512 remains
            const int k  = kg + (it << 6);
            const int c1 = ((it & 3) << 2) | (it >> 2);            // rev4(64it)
            const int j2 = (J0 - it) & 15;
            const int c2 = ((j2 & 3) << 2) | (j2 >> 2);
            const float2 z1 = zp1[c1];
            const float2 z2 = zp2[c2];
            // F_even[k] = (Z[k]+conj(Z[N-k]))/2 ; F_odd[k] = -i(Z[k]-conj(Z[N-k]))/2
            const float re_e = 0.5f*(z1.x + z2.x);
            const float im_e = 0.5f*(z1.y - z2.y);     // exact +0.0 at k=0,512
            const float re_o = 0.5f*(z1.y + z2.y);
            const float im_o = 0.5f*(z2.x - z1.x);
            *reinterpret_cast<float2*>(&magp[magbase + (size_t)k * NFRAMES]) =
                make_float2(fmaf(re_e, re_e, im_e*im_e), fmaf(re_o, re_o, im_o*im_o));
            const float ph_e = fast_atan2f(im_e, re_e);
            const float ph_o = fast_atan2f(im_o, re_o);
            *reinterpret_cast<float2*>(&php[phbase + (size_t)k * NFRAMES]) =
                make_float2(ph_e, ph_o);
            if (k != 0 && k != 512) {
                // atan2 is odd in y INCLUDING signed zeros -> mirror = sign flip
                *reinterpret_cast<float2*>(&php[phbase + (size_t)(NFFT - k) * NFRAMES]) =
                    make_float2(-ph_e, -ph_o);
            }
        }
    }
}

extern "C" void kernel_launch(void* const* d_in, const int* in_sizes, int n_in,
                              void* d_out, int out_size, void* d_ws, size_t ws_size,
                              hipStream_t stream) {
    const float* x  = (const float*)d_in[0];
    const float* rw = (const float*)d_in[1];   // row 0 = fp32 hanning window
    float* out = (float*)d_out;
    spec_kernel<<<dim3(NBLK, 1, 1), dim3(NT, 1, 1), 0, stream>>>(x, rw, out);
}